// Round 8
// baseline (680.775 us; speedup 1.0000x reference)
//
#include <hip/hip_runtime.h>
#include <cstdint>
#include <cstddef>

// Problem shape (fixed by setup_inputs): B=4, T=4096, E=1024
#define B_ 4
#define T_ 4096
#define E_ 1024
#define BT_ (B_*T_)

typedef unsigned short u16;
typedef unsigned int   u32;
typedef __attribute__((ext_vector_type(8))) short bf8;   // 8 x bf16 (4 VGPRs)
typedef __attribute__((ext_vector_type(4))) float f4;

union punAB { uint4 u; bf8 v; };   // legal type-pun (union, clang-supported)

__device__ inline u16 f2bf(float f){            // RNE float->bf16
  u32 x = __float_as_uint(f);
  u32 r = (x + 0x7fffu + ((x >> 16) & 1u)) >> 16;
  return (u16)r;
}
__device__ inline float bf2f(u32 u){ return __uint_as_float(u << 16); }

__device__ inline float wredsum(float v){
  #pragma unroll
  for (int o = 32; o; o >>= 1) v += __shfl_xor(v, o, 64);
  return v;
}

// raw hardware exp2 (no ocml denormal fixup); safe here: arg <= 0, underflow->0
__device__ inline float hw_exp2(float x){
#if __has_builtin(__builtin_amdgcn_exp2f)
  return __builtin_amdgcn_exp2f(x);
#else
  return exp2f(x);
#endif
}

// v_cvt_pk_bf16_f32: D[15:0]=bf16(a), D[31:16]=bf16(b)  (RNE)
__device__ inline u32 cvt_pk_bf16(float a, float b){
  u32 r;
  asm("v_cvt_pk_bf16_f32 %0, %1, %2" : "=v"(r) : "v"(a), "v"(b));
  return r;
}

// async global->LDS, 16B per lane; LDS dest is wave-uniform base + lane*16
__device__ inline void gld_lds16(const void* g, void* l){
  __builtin_amdgcn_global_load_lds(
      (const __attribute__((address_space(1))) void*)g,
      (__attribute__((address_space(3))) void*)l, 16, 0, 0);
}

#define LOG2E_ 1.44269504088896340f

// ---- K1: key/query scalars + bf16 token copy (one wave per row) ------------
__global__ __launch_bounds__(256) void k_prep(const float* __restrict__ token,
    const float* __restrict__ Wk, const float* __restrict__ bk,
    const float* __restrict__ Wq, const float* __restrict__ bq,
    float* __restrict__ key, float* __restrict__ query, u16* __restrict__ tokbf){
  int row  = blockIdx.x * 4 + (threadIdx.x >> 6);
  int lane = threadIdx.x & 63;
  const f4* tr = (const f4*)(token + (size_t)row * E_);
  const f4* wk = (const f4*)Wk;
  const f4* wq = (const f4*)Wq;
  float sk = 0.f, sq = 0.f;
  #pragma unroll
  for (int it = 0; it < 4; ++it){
    f4 t = tr[lane + 64*it];
    f4 a = wk[lane + 64*it];
    f4 b = wq[lane + 64*it];
    sk += t.x*a.x + t.y*a.y + t.z*a.z + t.w*a.w;
    sq += t.x*b.x + t.y*b.y + t.z*b.z + t.w*b.w;
    u32 lo = (u32)f2bf(t.x) | ((u32)f2bf(t.y) << 16);
    u32 hi = (u32)f2bf(t.z) | ((u32)f2bf(t.w) << 16);
    uint2 pk; pk.x = lo; pk.y = hi;
    *(uint2*)(tokbf + (size_t)row * E_ + (lane + 64*it)*4) = pk;
  }
  sk = wredsum(sk); sq = wredsum(sq);
  if (lane == 0){ key[row] = sk + bk[0]; query[row] = sq + bq[0]; }
}

// ---- K2: per-batch kmax/kmin ----------------------------------------------
__global__ __launch_bounds__(256) void k_stats(const float* __restrict__ key,
                                               float* __restrict__ kstat){
  int b = blockIdx.x;
  float mx = -3.4e38f, mn = 3.4e38f;
  for (int i = threadIdx.x; i < T_; i += 256){
    float v = key[b*T_ + i];
    mx = fmaxf(mx, v); mn = fminf(mn, v);
  }
  #pragma unroll
  for (int o = 32; o; o >>= 1){
    mx = fmaxf(mx, __shfl_xor(mx, o, 64));
    mn = fminf(mn, __shfl_xor(mn, o, 64));
  }
  __shared__ float smx[4], smn[4];
  int w = threadIdx.x >> 6;
  if ((threadIdx.x & 63) == 0){ smx[w] = mx; smn[w] = mn; }
  __syncthreads();
  if (threadIdx.x == 0){
    mx = fmaxf(fmaxf(smx[0], smx[1]), fmaxf(smx[2], smx[3]));
    mn = fminf(fminf(smn[0], smn[1]), fminf(smn[2], smn[3]));
    kstat[b*2] = mx; kstat[b*2+1] = mn;
  }
}

// ---- K3: softmax row max (analytic) + denominator (one wave per row) -------
__global__ __launch_bounds__(256) void k_denom(const float* __restrict__ key,
    const float* __restrict__ query, const float* __restrict__ kstat,
    float* __restrict__ mrow, float* __restrict__ drow){
  int row  = blockIdx.x * 4 + (threadIdx.x >> 6);
  int lane = threadIdx.x & 63;
  int b = row / T_;
  float q = query[row];
  float m = (q > 0.f) ? q * kstat[b*2] : q * kstat[b*2+1];
  float qL = q * LOG2E_, mL = m * LOG2E_;
  const float* kb = key + (size_t)b * T_;
  float s = 0.f;
  for (int x = lane; x < T_; x += 64) s += hw_exp2(qL * kb[x] - mL);
  s = wredsum(s);
  if (lane == 0){ mrow[row] = m; drow[row] = s; }
}

// ---- K4: Wv (fp32 [k][n]) -> WvT (bf16 [n][k]) -----------------------------
__global__ __launch_bounds__(256) void k_wvT(const float* __restrict__ Wv,
                                             u16* __restrict__ wvT){
  __shared__ u16 tile[32][33];
  int nt = blockIdx.x, kt = blockIdx.y;
  int tx = threadIdx.x & 31, ty0 = threadIdx.x >> 5;
  #pragma unroll
  for (int p = 0; p < 4; ++p){
    int ty = ty0 + p*8;
    tile[ty][tx] = f2bf(Wv[(size_t)(kt*32+ty)*E_ + nt*32 + tx]);
  }
  __syncthreads();
  #pragma unroll
  for (int p = 0; p < 4; ++p){
    int ty = ty0 + p*8;
    wvT[(size_t)(nt*32+ty)*E_ + kt*32 + tx] = tile[tx][ty];
  }
}

// ---- GEMM: 128x128 tile, 4 waves (2x2, wave tile 64x64), BK=32 -------------
// (unchanged, validated in rounds 2-6)
template<int MODE>
__global__ __launch_bounds__(256) void k_gemm(const u16* __restrict__ A,
    const u16* __restrict__ Bt, const float* __restrict__ bias,
    const u16* __restrict__ resid, u16* __restrict__ outp){
  __shared__ __align__(16) u16 lA[128*32];
  __shared__ __align__(16) u16 lB[128*32];
  const int K = E_, N = E_;
  int bid = blockIdx.x;
  int xcd = bid & 7, rr = bid >> 3;
  int m0 = (xcd + (rr >> 3)*8) * 128;
  int n0 = (rr & 7) * 128;
  int tid = threadIdx.x, lane = tid & 63, w = tid >> 6;
  int wr = w >> 1, wc = w & 1, h = lane >> 4, l15 = lane & 15;
  f4 acc[4][4] = {};
  for (int k0 = 0; k0 < K; k0 += 32){
    __syncthreads();
    #pragma unroll
    for (int p = 0; p < 2; ++p){
      int u = p*256 + w*64 + lane;
      int row = u >> 2;
      int sl  = (u & 3) ^ ((row >> 1) & 3);
      const u16* ga = A  + (size_t)(m0 + row) * K + k0 + sl*8;
      const u16* gb = Bt + (size_t)(n0 + row) * K + k0 + sl*8;
      gld_lds16(ga, lA + (size_t)(p*256 + w*64)*8);
      gld_lds16(gb, lB + (size_t)(p*256 + w*64)*8);
    }
    __syncthreads();
    bf8 a[4], bfr[4];
    #pragma unroll
    for (int f = 0; f < 4; ++f){
      int ra = wr*64 + f*16 + l15;
      int rb = wc*64 + f*16 + l15;
      a[f]   = *(const bf8*)&lA[ra*32 + ((h ^ ((ra >> 1) & 3)) & 3)*8];
      bfr[f] = *(const bf8*)&lB[rb*32 + ((h ^ ((rb >> 1) & 3)) & 3)*8];
    }
    #pragma unroll
    for (int fm = 0; fm < 4; ++fm)
    #pragma unroll
    for (int fn = 0; fn < 4; ++fn)
      acc[fm][fn] = __builtin_amdgcn_mfma_f32_16x16x32_bf16(a[fm], bfr[fn], acc[fm][fn], 0,0,0);
  }
  if (MODE == 0){
    #pragma unroll
    for (int fm = 0; fm < 4; ++fm){
      int rowg = m0 + wr*64 + fm*16 + h*4;
      int bb = rowg >> 12;
      int tt = rowg & (T_-1);
      #pragma unroll
      for (int fn = 0; fn < 4; ++fn){
        int col = n0 + wc*64 + fn*16 + l15;
        float bv = bias[col];
        u16 q0 = f2bf(acc[fm][fn][0] + bv);
        u16 q1 = f2bf(acc[fm][fn][1] + bv);
        u16 q2 = f2bf(acc[fm][fn][2] + bv);
        u16 q3 = f2bf(acc[fm][fn][3] + bv);
        uint2 pk; pk.x = (u32)q0 | ((u32)q1 << 16); pk.y = (u32)q2 | ((u32)q3 << 16);
        *(uint2*)(outp + ((size_t)bb*E_ + col)*T_ + tt) = pk;
      }
    }
  } else {
    #pragma unroll
    for (int fm = 0; fm < 4; ++fm)
    #pragma unroll
    for (int fn = 0; fn < 4; ++fn)
    #pragma unroll
    for (int r = 0; r < 4; ++r){
      int row = m0 + wr*64 + fm*16 + h*4 + r;
      int col = n0 + wc*64 + fn*16 + l15;
      float v = acc[fm][fn][r] + bias[col] + bf2f(resid[(size_t)row * N + col]);
      outp[(size_t)row * N + col] = f2bf(v);
    }
  }
}

// ---- K7 v8: PV — wave 32t x 128e; round-6 proven loop shape, half the acc ---
// acc[2][8] = 64 AGPRs (was 128) -> ~200 unified regs -> 2 waves/SIMD.
// Block = 4 t-stacked waves (128t x 128e) sharing identical V loads each step
// (L1 broadcast, 4x less L2 traffic). Grid: each (b, e-slice) stripe (V work-
// ing set 1 MB) pinned to one XCD via bid&7. No LDS, no barriers, no inline
// waitcnt -- depth-1 register prefetch with masked wrap (validated round 6).
__global__ __launch_bounds__(256) void k_pv(const float* __restrict__ query,
    const float* __restrict__ key, const float* __restrict__ mrow,
    const float* __restrict__ drow, const u16* __restrict__ valT,
    u16* __restrict__ zraw){
  int bid = blockIdx.x;                         // 1024 blocks
  int xcd = bid & 7, r = bid >> 3;              // r: 0..127
  int t0b = (r & 31) * 128;                     // t-block (128 rows)
  int sl  = (xcd << 2) | (r >> 5);              // 0..31 = (b, e-slice)
  int b   = sl >> 3;
  int e0  = (sl & 7) * 128;
  int w = threadIdx.x >> 6, lane = threadIdx.x & 63;
  int h = lane >> 4, l15 = lane & 15;
  int tw = t0b + w*32;                          // wave's 32 t-rows

  float qv[2], mv[2];
  #pragma unroll
  for (int fm = 0; fm < 2; ++fm){
    int row = tw + fm*16 + l15;
    qv[fm] = query[b*T_ + row] * LOG2E_;
    mv[fm] = mrow [b*T_ + row] * LOG2E_;
  }
  const float* kp = key + (size_t)b * T_ + h*8;  // lane's 8 k-cols at x0+8h
  const u16*   vb = valT + (size_t)b * E_ * T_
                         + (size_t)(e0 + l15) * T_ + h*8;   // same for all 4 waves
  f4 acc[2][8] = {};

  // prefetch step 0
  f4 ka = *(const f4*)(kp);
  f4 kc = *(const f4*)(kp + 4);
  bf8 vr0 = *(const bf8*)(vb);
  bf8 vr1 = *(const bf8*)(vb + (size_t)16*T_);
  bf8 vr2 = *(const bf8*)(vb + (size_t)32*T_);
  bf8 vr3 = *(const bf8*)(vb + (size_t)48*T_);
  bf8 vr4 = *(const bf8*)(vb + (size_t)64*T_);
  bf8 vr5 = *(const bf8*)(vb + (size_t)80*T_);
  bf8 vr6 = *(const bf8*)(vb + (size_t)96*T_);
  bf8 vr7 = *(const bf8*)(vb + (size_t)112*T_);

  for (int x0 = 0; x0 < T_; x0 += 32){
    // issue next-step prefetch (masked wrap on last iter; values unused then)
    int xn = (x0 + 32) & (T_ - 1);
    f4 kna = *(const f4*)(kp + xn);
    f4 knc = *(const f4*)(kp + xn + 4);
    bf8 vn0 = *(const bf8*)(vb + xn);
    bf8 vn1 = *(const bf8*)(vb + (size_t)16*T_ + xn);
    bf8 vn2 = *(const bf8*)(vb + (size_t)32*T_ + xn);
    bf8 vn3 = *(const bf8*)(vb + (size_t)48*T_ + xn);
    bf8 vn4 = *(const bf8*)(vb + (size_t)64*T_ + xn);
    bf8 vn5 = *(const bf8*)(vb + (size_t)80*T_ + xn);
    bf8 vn6 = *(const bf8*)(vb + (size_t)96*T_ + xn);
    bf8 vn7 = *(const bf8*)(vb + (size_t)112*T_ + xn);
    // compute on current set (ready since last step)
    #pragma unroll
    for (int fm = 0; fm < 2; ++fm){
      float q = qv[fm], m = mv[fm];
      float p0 = hw_exp2(q*ka.x - m), p1 = hw_exp2(q*ka.y - m);
      float p2 = hw_exp2(q*ka.z - m), p3 = hw_exp2(q*ka.w - m);
      float p4 = hw_exp2(q*kc.x - m), p5 = hw_exp2(q*kc.y - m);
      float p6 = hw_exp2(q*kc.z - m), p7 = hw_exp2(q*kc.w - m);
      punAB pa;
      pa.u.x = cvt_pk_bf16(p0, p1);
      pa.u.y = cvt_pk_bf16(p2, p3);
      pa.u.z = cvt_pk_bf16(p4, p5);
      pa.u.w = cvt_pk_bf16(p6, p7);
      bf8 af = pa.v;
      acc[fm][0] = __builtin_amdgcn_mfma_f32_16x16x32_bf16(af, vr0, acc[fm][0], 0,0,0);
      acc[fm][1] = __builtin_amdgcn_mfma_f32_16x16x32_bf16(af, vr1, acc[fm][1], 0,0,0);
      acc[fm][2] = __builtin_amdgcn_mfma_f32_16x16x32_bf16(af, vr2, acc[fm][2], 0,0,0);
      acc[fm][3] = __builtin_amdgcn_mfma_f32_16x16x32_bf16(af, vr3, acc[fm][3], 0,0,0);
      acc[fm][4] = __builtin_amdgcn_mfma_f32_16x16x32_bf16(af, vr4, acc[fm][4], 0,0,0);
      acc[fm][5] = __builtin_amdgcn_mfma_f32_16x16x32_bf16(af, vr5, acc[fm][5], 0,0,0);
      acc[fm][6] = __builtin_amdgcn_mfma_f32_16x16x32_bf16(af, vr6, acc[fm][6], 0,0,0);
      acc[fm][7] = __builtin_amdgcn_mfma_f32_16x16x32_bf16(af, vr7, acc[fm][7], 0,0,0);
    }
    ka = kna; kc = knc;
    vr0 = vn0; vr1 = vn1; vr2 = vn2; vr3 = vn3;
    vr4 = vn4; vr5 = vn5; vr6 = vn6; vr7 = vn7;
  }

  #pragma unroll
  for (int fm = 0; fm < 2; ++fm){
    #pragma unroll
    for (int rr = 0; rr < 4; ++rr){
      int row = tw + fm*16 + h*4 + rr;
      float inv = 1.f / drow[b*T_ + row];
      #pragma unroll
      for (int fn = 0; fn < 8; ++fn){
        int col = e0 + fn*16 + l15;
        zraw[((size_t)b*T_ + row)*E_ + col] = f2bf(acc[fm][fn][rr] * inv);
      }
    }
  }
}

// ---- LN (one wave per row). FINAL=0: bf16 out. FINAL=1: relu -> fp32 out ---
template<int FINAL>
__global__ __launch_bounds__(256) void k_ln(const u16* __restrict__ in,
    const float* __restrict__ g, const float* __restrict__ bt,
    void* __restrict__ outp){
  int row  = blockIdx.x * 4 + (threadIdx.x >> 6);
  int lane = threadIdx.x & 63;
  const u16* r = in + (size_t)row * E_;
  uint4 u0 = *(const uint4*)(r + lane*16);
  uint4 u1 = *(const uint4*)(r + lane*16 + 8);
  u32 uu[8] = {u0.x, u0.y, u0.z, u0.w, u1.x, u1.y, u1.z, u1.w};
  float v[16];
  #pragma unroll
  for (int j = 0; j < 8; ++j){
    v[2*j]   = bf2f(uu[j] & 0xffffu);
    v[2*j+1] = bf2f(uu[j] >> 16);
  }
  float s1 = 0.f, s2 = 0.f;
  #pragma unroll
  for (int j = 0; j < 16; ++j){ s1 += v[j]; s2 += v[j]*v[j]; }
  s1 = wredsum(s1); s2 = wredsum(s2);
  float mean = s1 * (1.f/E_);
  float var  = s2 * (1.f/E_) - mean*mean;
  float rs   = rsqrtf(var + 1e-3f);
  const f4* g4 = (const f4*)g + lane*4;
  const f4* b4 = (const f4*)bt + lane*4;
  float o[16];
  #pragma unroll
  for (int jj = 0; jj < 4; ++jj){
    f4 gg = g4[jj], bb = b4[jj];
    o[4*jj+0] = (v[4*jj+0]-mean)*rs*gg.x + bb.x;
    o[4*jj+1] = (v[4*jj+1]-mean)*rs*gg.y + bb.y;
    o[4*jj+2] = (v[4*jj+2]-mean)*rs*gg.z + bb.z;
    o[4*jj+3] = (v[4*jj+3]-mean)*rs*gg.w + bb.w;
  }
  if (FINAL){
    f4* od = (f4*)((float*)outp + (size_t)row * E_ + lane*16);
    #pragma unroll
    for (int jj = 0; jj < 4; ++jj){
      f4 t;
      t.x = fmaxf(o[4*jj+0], 0.f); t.y = fmaxf(o[4*jj+1], 0.f);
      t.z = fmaxf(o[4*jj+2], 0.f); t.w = fmaxf(o[4*jj+3], 0.f);
      od[jj] = t;
    }
  } else {
    u16* ob = (u16*)outp + (size_t)row * E_ + lane*16;
    u32 pu[8];
    #pragma unroll
    for (int j = 0; j < 8; ++j)
      pu[j] = (u32)f2bf(o[2*j]) | ((u32)f2bf(o[2*j+1]) << 16);
    uint4 w0 = {pu[0], pu[1], pu[2], pu[3]};
    uint4 w1 = {pu[4], pu[5], pu[6], pu[7]};
    *(uint4*)ob       = w0;
    *(uint4*)(ob + 8) = w1;
  }
}

// ---------------------------------------------------------------------------
extern "C" void kernel_launch(void* const* d_in, const int* in_sizes, int n_in,
                              void* d_out, int out_size, void* d_ws, size_t ws_size,
                              hipStream_t stream){
  const float* token = (const float*)d_in[0];
  const float* Wk    = (const float*)d_in[1];
  const float* bk    = (const float*)d_in[2];
  const float* Wq    = (const float*)d_in[3];
  const float* bq    = (const float*)d_in[4];
  const float* Wv    = (const float*)d_in[5];
  const float* bv    = (const float*)d_in[6];
  const float* g1    = (const float*)d_in[7];
  const float* b1    = (const float*)d_in[8];
  const float* g2    = (const float*)d_in[9];
  const float* b2    = (const float*)d_in[10];

  char* ws = (char*)d_ws;
  u16*   wvT   = (u16*)ws;
  float* key   = (float*)(ws + (2u<<20));
  float* query = (float*)(ws + (2u<<20) + (64u<<10));
  float* mrow  = (float*)(ws + (2u<<20) + (128u<<10));
  float* drow  = (float*)(ws + (2u<<20) + (192u<<10));
  float* kstat = (float*)(ws + (2u<<20) + (256u<<10));
  u16* X = (u16*)(ws + (4u<<20));
  u16* V = (u16*)(ws + (36u<<20));
  float* out = (float*)d_out;

  k_prep <<<dim3(BT_/4), 256, 0, stream>>>(token, Wk, bk, Wq, bq, key, query, X);
  k_stats<<<dim3(B_),    256, 0, stream>>>(key, kstat);
  k_denom<<<dim3(BT_/4), 256, 0, stream>>>(key, query, kstat, mrow, drow);
  k_wvT  <<<dim3(E_/32, E_/32), 256, 0, stream>>>(Wv, wvT);
  // value GEMM: A=token_bf16 (X), writes valT directly (V)
  k_gemm<0><<<dim3((BT_/128)*(E_/128)), 256, 0, stream>>>(X, wvT, bv, nullptr, V);
  // PV: reads valT (V), writes zraw (X; token_bf dead)
  k_pv   <<<dim3((T_/128)*(E_/128)*B_), 256, 0, stream>>>(query, key, mrow, drow, V, X);
  // LN1: X -> V (z1; valT dead)
  k_ln<0><<<dim3(BT_/4), 256, 0, stream>>>(X, g1, b1, (void*)V);
  // gemm2 + residual: A=resid=z1 (V), writes y (X)
  k_gemm<1><<<dim3((BT_/128)*(E_/128)), 256, 0, stream>>>(V, wvT, bv, V, X);
  // LN2 + relu: X -> out (fp32)
  k_ln<1><<<dim3(BT_/4), 256, 0, stream>>>(X, g2, b2, (void*)out);
}

// Round 9
// 258.934 us; speedup vs baseline: 2.6291x; 2.6291x over previous
//
#include <hip/hip_runtime.h>
#include <cstdint>
#include <cstddef>

// Problem shape (fixed by setup_inputs): B=4, T=4096, E=1024
#define B_ 4
#define T_ 4096
#define E_ 1024
#define BT_ (B_*T_)
#define G_ 1024          // q-grid nodes per batch

typedef unsigned short u16;
typedef unsigned int   u32;
typedef __attribute__((ext_vector_type(8))) short bf8;   // 8 x bf16 (4 VGPRs)
typedef __attribute__((ext_vector_type(4))) float f4;

__device__ inline u16 f2bf(float f){            // RNE float->bf16
  u32 x = __float_as_uint(f);
  u32 r = (x + 0x7fffu + ((x >> 16) & 1u)) >> 16;
  return (u16)r;
}
__device__ inline float bf2f(u32 u){ return __uint_as_float(u << 16); }

__device__ inline float wredsum(float v){
  #pragma unroll
  for (int o = 32; o; o >>= 1) v += __shfl_xor(v, o, 64);
  return v;
}

// raw hardware exp2 (no ocml denormal fixup); safe here: arg <= 0, underflow->0
__device__ inline float hw_exp2(float x){
#if __has_builtin(__builtin_amdgcn_exp2f)
  return __builtin_amdgcn_exp2f(x);
#else
  return exp2f(x);
#endif
}

// async global->LDS, 16B per lane; LDS dest is wave-uniform base + lane*16
__device__ inline void gld_lds16(const void* g, void* l){
  __builtin_amdgcn_global_load_lds(
      (const __attribute__((address_space(1))) void*)g,
      (__attribute__((address_space(3))) void*)l, 16, 0, 0);
}

#define LOG2E_ 1.44269504088896340f

// ---- K1: key/query scalars + bf16 token copy (one wave per row) ------------
__global__ __launch_bounds__(256) void k_prep(const float* __restrict__ token,
    const float* __restrict__ Wk, const float* __restrict__ bk,
    const float* __restrict__ Wq, const float* __restrict__ bq,
    float* __restrict__ key, float* __restrict__ query, u16* __restrict__ tokbf){
  int row  = blockIdx.x * 4 + (threadIdx.x >> 6);
  int lane = threadIdx.x & 63;
  const f4* tr = (const f4*)(token + (size_t)row * E_);
  const f4* wk = (const f4*)Wk;
  const f4* wq = (const f4*)Wq;
  float sk = 0.f, sq = 0.f;
  #pragma unroll
  for (int it = 0; it < 4; ++it){
    f4 t = tr[lane + 64*it];
    f4 a = wk[lane + 64*it];
    f4 b = wq[lane + 64*it];
    sk += t.x*a.x + t.y*a.y + t.z*a.z + t.w*a.w;
    sq += t.x*b.x + t.y*b.y + t.z*b.z + t.w*b.w;
    u32 lo = (u32)f2bf(t.x) | ((u32)f2bf(t.y) << 16);
    u32 hi = (u32)f2bf(t.z) | ((u32)f2bf(t.w) << 16);
    uint2 pk; pk.x = lo; pk.y = hi;
    *(uint2*)(tokbf + (size_t)row * E_ + (lane + 64*it)*4) = pk;
  }
  sk = wredsum(sk); sq = wredsum(sq);
  if (lane == 0){ key[row] = sk + bk[0]; query[row] = sq + bq[0]; }
}

// ---- K2: per-batch kmax/kmin/qmax/qmin -------------------------------------
__global__ __launch_bounds__(256) void k_stats(const float* __restrict__ key,
    const float* __restrict__ query, float* __restrict__ kstat){
  int b = blockIdx.x;
  float kmx = -3.4e38f, kmn = 3.4e38f, qmx = -3.4e38f, qmn = 3.4e38f;
  for (int i = threadIdx.x; i < T_; i += 256){
    float kv = key[b*T_ + i], qv = query[b*T_ + i];
    kmx = fmaxf(kmx, kv); kmn = fminf(kmn, kv);
    qmx = fmaxf(qmx, qv); qmn = fminf(qmn, qv);
  }
  #pragma unroll
  for (int o = 32; o; o >>= 1){
    kmx = fmaxf(kmx, __shfl_xor(kmx, o, 64));
    kmn = fminf(kmn, __shfl_xor(kmn, o, 64));
    qmx = fmaxf(qmx, __shfl_xor(qmx, o, 64));
    qmn = fminf(qmn, __shfl_xor(qmn, o, 64));
  }
  __shared__ float sh[4][4];
  int w = threadIdx.x >> 6;
  if ((threadIdx.x & 63) == 0){
    sh[w][0] = kmx; sh[w][1] = kmn; sh[w][2] = qmx; sh[w][3] = qmn;
  }
  __syncthreads();
  if (threadIdx.x == 0){
    kmx = fmaxf(fmaxf(sh[0][0], sh[1][0]), fmaxf(sh[2][0], sh[3][0]));
    kmn = fminf(fminf(sh[0][1], sh[1][1]), fminf(sh[2][1], sh[3][1]));
    qmx = fmaxf(fmaxf(sh[0][2], sh[1][2]), fmaxf(sh[2][2], sh[3][2]));
    qmn = fminf(fminf(sh[0][3], sh[1][3]), fminf(sh[2][3], sh[3][3]));
    kstat[b*4+0] = kmx; kstat[b*4+1] = kmn;
    kstat[b*4+2] = qmx; kstat[b*4+3] = qmn;
  }
}

// ---- K4: Wv (fp32 [k][n]) -> WvT (bf16 [n][k]) -----------------------------
__global__ __launch_bounds__(256) void k_wvT(const float* __restrict__ Wv,
                                             u16* __restrict__ wvT){
  __shared__ u16 tile[32][33];
  int nt = blockIdx.x, kt = blockIdx.y;
  int tx = threadIdx.x & 31, ty0 = threadIdx.x >> 5;
  #pragma unroll
  for (int p = 0; p < 4; ++p){
    int ty = ty0 + p*8;
    tile[ty][tx] = f2bf(Wv[(size_t)(kt*32+ty)*E_ + nt*32 + tx]);
  }
  __syncthreads();
  #pragma unroll
  for (int p = 0; p < 4; ++p){
    int ty = ty0 + p*8;
    wvT[(size_t)(nt*32+ty)*E_ + kt*32 + tx] = tile[tx][ty];
  }
}

// ---- GEMM: 128x128 tile, 4 waves (2x2, wave tile 64x64), BK=32 -------------
// (unchanged, validated in rounds 2-8)
template<int MODE>
__global__ __launch_bounds__(256) void k_gemm(const u16* __restrict__ A,
    const u16* __restrict__ Bt, const float* __restrict__ bias,
    const u16* __restrict__ resid, u16* __restrict__ outp){
  __shared__ __align__(16) u16 lA[128*32];
  __shared__ __align__(16) u16 lB[128*32];
  const int K = E_, N = E_;
  int bid = blockIdx.x;
  int xcd = bid & 7, rr = bid >> 3;
  int m0 = (xcd + (rr >> 3)*8) * 128;
  int n0 = (rr & 7) * 128;
  int tid = threadIdx.x, lane = tid & 63, w = tid >> 6;
  int wr = w >> 1, wc = w & 1, h = lane >> 4, l15 = lane & 15;
  f4 acc[4][4] = {};
  for (int k0 = 0; k0 < K; k0 += 32){
    __syncthreads();
    #pragma unroll
    for (int p = 0; p < 2; ++p){
      int u = p*256 + w*64 + lane;
      int row = u >> 2;
      int sl  = (u & 3) ^ ((row >> 1) & 3);
      const u16* ga = A  + (size_t)(m0 + row) * K + k0 + sl*8;
      const u16* gb = Bt + (size_t)(n0 + row) * K + k0 + sl*8;
      gld_lds16(ga, lA + (size_t)(p*256 + w*64)*8);
      gld_lds16(gb, lB + (size_t)(p*256 + w*64)*8);
    }
    __syncthreads();
    bf8 a[4], bfr[4];
    #pragma unroll
    for (int f = 0; f < 4; ++f){
      int ra = wr*64 + f*16 + l15;
      int rb = wc*64 + f*16 + l15;
      a[f]   = *(const bf8*)&lA[ra*32 + ((h ^ ((ra >> 1) & 3)) & 3)*8];
      bfr[f] = *(const bf8*)&lB[rb*32 + ((h ^ ((rb >> 1) & 3)) & 3)*8];
    }
    #pragma unroll
    for (int fm = 0; fm < 4; ++fm)
    #pragma unroll
    for (int fn = 0; fn < 4; ++fn)
      acc[fm][fn] = __builtin_amdgcn_mfma_f32_16x16x32_bf16(a[fm], bfr[fn], acc[fm][fn], 0,0,0);
  }
  if (MODE == 0){
    #pragma unroll
    for (int fm = 0; fm < 4; ++fm){
      int rowg = m0 + wr*64 + fm*16 + h*4;
      int bb = rowg >> 12;
      int tt = rowg & (T_-1);
      #pragma unroll
      for (int fn = 0; fn < 4; ++fn){
        int col = n0 + wc*64 + fn*16 + l15;
        float bv = bias[col];
        u16 q0 = f2bf(acc[fm][fn][0] + bv);
        u16 q1 = f2bf(acc[fm][fn][1] + bv);
        u16 q2 = f2bf(acc[fm][fn][2] + bv);
        u16 q3 = f2bf(acc[fm][fn][3] + bv);
        uint2 pk; pk.x = (u32)q0 | ((u32)q1 << 16); pk.y = (u32)q2 | ((u32)q3 << 16);
        *(uint2*)(outp + ((size_t)bb*E_ + col)*T_ + tt) = pk;
      }
    }
  } else {
    #pragma unroll
    for (int fm = 0; fm < 4; ++fm)
    #pragma unroll
    for (int fn = 0; fn < 4; ++fn)
    #pragma unroll
    for (int r = 0; r < 4; ++r){
      int row = m0 + wr*64 + fm*16 + h*4 + r;
      int col = n0 + wc*64 + fn*16 + l15;
      float v = acc[fm][fn][r] + bias[col] + bf2f(resid[(size_t)row * N + col]);
      outp[(size_t)row * N + col] = f2bf(v);
    }
  }
}

// ---- K5: P'-gen — P'[b*G+i][x] = bf16(exp2(g_i k_x - m_i)), d_i = row sum ---
// One wave per grid node. g_i = qmin + i*(qmax-qmin)/(G-1); m_i analytic.
__global__ __launch_bounds__(256) void k_pgen(const float* __restrict__ key,
    const float* __restrict__ kstat, u16* __restrict__ P,
    float* __restrict__ dnode){
  int r    = blockIdx.x * 4 + (threadIdx.x >> 6);   // 0..B*G-1
  int lane = threadIdx.x & 63;
  int b = r >> 10, i = r & (G_-1);
  float kmax = kstat[b*4+0], kmin = kstat[b*4+1];
  float qmax = kstat[b*4+2], qmin = kstat[b*4+3];
  float g = qmin + (qmax - qmin) * ((float)i * (1.f/(G_-1)));
  float m = (g > 0.f) ? g*kmax : g*kmin;
  float gL = g * LOG2E_, mL = m * LOG2E_;
  const f4* kb = (const f4*)(key + (size_t)b * T_);
  u16* pr = P + (size_t)r * T_;
  float s = 0.f;
  #pragma unroll 4
  for (int it = 0; it < 16; ++it){
    f4 kv = kb[lane + it*64];
    u16 e0 = f2bf(hw_exp2(gL*kv.x - mL));
    u16 e1 = f2bf(hw_exp2(gL*kv.y - mL));
    u16 e2 = f2bf(hw_exp2(gL*kv.z - mL));
    u16 e3 = f2bf(hw_exp2(gL*kv.w - mL));
    s += bf2f(e0) + bf2f(e1) + bf2f(e2) + bf2f(e3);   // d matches what GEMM sums
    uint2 pk;
    pk.x = (u32)e0 | ((u32)e1 << 16);
    pk.y = (u32)e2 | ((u32)e3 << 16);
    *(uint2*)(pr + (size_t)(lane + it*64)*4) = pk;
  }
  s = wredsum(s);
  if (lane == 0) dnode[r] = s;
}

// ---- K6: F-GEMM — F[b*G+i][e] = (P' @ valT^T)/d_i --------------------------
// M=B*G=4096, N=E, K=T. 128x64 tiles, 4 waves (2x2, wave 64x32) -> 512 blocks
// (2/CU). Same staging/swizzle discipline as k_gemm. Per-batch B panel.
__global__ __launch_bounds__(256) void k_fgemm(const u16* __restrict__ A,
    const u16* __restrict__ Vt, const float* __restrict__ dnode,
    float* __restrict__ F){
  __shared__ __align__(16) u16 lA[128*32];
  __shared__ __align__(16) u16 lB[64*32];
  const int K = T_;
  int bid = blockIdx.x;                 // 512 blocks = 32 m-tiles x 16 n-tiles
  int n0 = (bid & 15) * 64;
  int m0 = (bid >> 4) * 128;
  int b  = m0 >> 10;                    // G_=1024 rows per batch
  const u16* Bt = Vt + (size_t)b * E_ * T_;
  int tid = threadIdx.x, lane = tid & 63, w = tid >> 6;
  int wr = w >> 1, wc = w & 1, h = lane >> 4, l15 = lane & 15;
  f4 acc[4][2] = {};
  for (int k0 = 0; k0 < K; k0 += 32){
    __syncthreads();
    #pragma unroll
    for (int p = 0; p < 3; ++p){        // 2x A (128 rows) + 1x B (64 rows)
      int u = p*256 + w*64 + lane;
      if (p < 2){
        int row = u >> 2;
        int sl  = (u & 3) ^ ((row >> 1) & 3);
        gld_lds16(A + (size_t)(m0 + row) * K + k0 + sl*8,
                  lA + (size_t)(p*256 + w*64)*8);
      } else {
        int v = u - 512;
        int row = v >> 2;
        int sl  = (v & 3) ^ ((row >> 1) & 3);
        gld_lds16(Bt + (size_t)(n0 + row) * K + k0 + sl*8,
                  lB + (size_t)(w*64)*8);
      }
    }
    __syncthreads();
    bf8 a[4], bb[2];
    #pragma unroll
    for (int f = 0; f < 4; ++f){
      int ra = wr*64 + f*16 + l15;
      a[f] = *(const bf8*)&lA[ra*32 + ((h ^ ((ra >> 1) & 3)) & 3)*8];
    }
    #pragma unroll
    for (int f = 0; f < 2; ++f){
      int rb = wc*32 + f*16 + l15;
      bb[f] = *(const bf8*)&lB[rb*32 + ((h ^ ((rb >> 1) & 3)) & 3)*8];
    }
    #pragma unroll
    for (int fm = 0; fm < 4; ++fm)
    #pragma unroll
    for (int fn = 0; fn < 2; ++fn)
      acc[fm][fn] = __builtin_amdgcn_mfma_f32_16x16x32_bf16(a[fm], bb[fn], acc[fm][fn], 0,0,0);
  }
  #pragma unroll
  for (int fm = 0; fm < 4; ++fm)
  #pragma unroll
  for (int r = 0; r < 4; ++r){
    int row = m0 + wr*64 + fm*16 + h*4 + r;
    float inv = 1.f / dnode[row];
    #pragma unroll
    for (int fn = 0; fn < 2; ++fn){
      int col = n0 + wc*32 + fn*16 + l15;
      F[(size_t)row * E_ + col] = acc[fm][fn][r] * inv;
    }
  }
}

// ---- K7: interp + LN1 fused — z1[t] = LN(lerp(F, q_t)) ---------------------
__global__ __launch_bounds__(256) void k_lni(const float* __restrict__ query,
    const float* __restrict__ kstat, const float* __restrict__ F,
    const float* __restrict__ g, const float* __restrict__ bt,
    u16* __restrict__ z1){
  int row  = blockIdx.x * 4 + (threadIdx.x >> 6);   // 0..BT-1
  int lane = threadIdx.x & 63;
  int b = row >> 12;                                // T_=4096
  float qmax = kstat[b*4+2], qmin = kstat[b*4+3];
  float q = query[row];
  float u = (q - qmin) * ((float)(G_-1) / (qmax - qmin));
  int i = (int)u;
  if (i < 0) i = 0;
  if (i > G_-2) i = G_-2;
  float a = fminf(fmaxf(u - (float)i, 0.f), 1.f);
  const f4* F0 = (const f4*)(F + ((size_t)(b*G_ + i)) * E_) + lane*4;
  const f4* F1 = F0 + (E_/4);
  float v[16];
  #pragma unroll
  for (int jj = 0; jj < 4; ++jj){
    f4 x0 = F0[jj], x1 = F1[jj];
    v[4*jj+0] = x0.x + a*(x1.x - x0.x);
    v[4*jj+1] = x0.y + a*(x1.y - x0.y);
    v[4*jj+2] = x0.z + a*(x1.z - x0.z);
    v[4*jj+3] = x0.w + a*(x1.w - x0.w);
  }
  float s1 = 0.f, s2 = 0.f;
  #pragma unroll
  for (int j = 0; j < 16; ++j){ s1 += v[j]; s2 += v[j]*v[j]; }
  s1 = wredsum(s1); s2 = wredsum(s2);
  float mean = s1 * (1.f/E_);
  float var  = s2 * (1.f/E_) - mean*mean;
  float rs   = rsqrtf(var + 1e-3f);
  const f4* g4 = (const f4*)g + lane*4;
  const f4* b4 = (const f4*)bt + lane*4;
  u16* ob = z1 + (size_t)row * E_ + lane*16;
  u32 pu[8];
  #pragma unroll
  for (int jj = 0; jj < 4; ++jj){
    f4 gg = g4[jj], bb = b4[jj];
    float o0 = (v[4*jj+0]-mean)*rs*gg.x + bb.x;
    float o1 = (v[4*jj+1]-mean)*rs*gg.y + bb.y;
    float o2 = (v[4*jj+2]-mean)*rs*gg.z + bb.z;
    float o3 = (v[4*jj+3]-mean)*rs*gg.w + bb.w;
    pu[2*jj]   = (u32)f2bf(o0) | ((u32)f2bf(o1) << 16);
    pu[2*jj+1] = (u32)f2bf(o2) | ((u32)f2bf(o3) << 16);
  }
  uint4 w0 = {pu[0], pu[1], pu[2], pu[3]};
  uint4 w1 = {pu[4], pu[5], pu[6], pu[7]};
  *(uint4*)ob       = w0;
  *(uint4*)(ob + 8) = w1;
}

// ---- LN2 + relu -> fp32 out (unchanged FINAL=1 path) ------------------------
__global__ __launch_bounds__(256) void k_ln2(const u16* __restrict__ in,
    const float* __restrict__ g, const float* __restrict__ bt,
    float* __restrict__ outp){
  int row  = blockIdx.x * 4 + (threadIdx.x >> 6);
  int lane = threadIdx.x & 63;
  const u16* r = in + (size_t)row * E_;
  uint4 u0 = *(const uint4*)(r + lane*16);
  uint4 u1 = *(const uint4*)(r + lane*16 + 8);
  u32 uu[8] = {u0.x, u0.y, u0.z, u0.w, u1.x, u1.y, u1.z, u1.w};
  float v[16];
  #pragma unroll
  for (int j = 0; j < 8; ++j){
    v[2*j]   = bf2f(uu[j] & 0xffffu);
    v[2*j+1] = bf2f(uu[j] >> 16);
  }
  float s1 = 0.f, s2 = 0.f;
  #pragma unroll
  for (int j = 0; j < 16; ++j){ s1 += v[j]; s2 += v[j]*v[j]; }
  s1 = wredsum(s1); s2 = wredsum(s2);
  float mean = s1 * (1.f/E_);
  float var  = s2 * (1.f/E_) - mean*mean;
  float rs   = rsqrtf(var + 1e-3f);
  const f4* g4 = (const f4*)g + lane*4;
  const f4* b4 = (const f4*)bt + lane*4;
  f4* od = (f4*)(outp + (size_t)row * E_ + lane*16);
  #pragma unroll
  for (int jj = 0; jj < 4; ++jj){
    f4 gg = g4[jj], bb = b4[jj];
    f4 t;
    t.x = fmaxf((v[4*jj+0]-mean)*rs*gg.x + bb.x, 0.f);
    t.y = fmaxf((v[4*jj+1]-mean)*rs*gg.y + bb.y, 0.f);
    t.z = fmaxf((v[4*jj+2]-mean)*rs*gg.z + bb.z, 0.f);
    t.w = fmaxf((v[4*jj+3]-mean)*rs*gg.w + bb.w, 0.f);
    od[jj] = t;
  }
}

// ---------------------------------------------------------------------------
extern "C" void kernel_launch(void* const* d_in, const int* in_sizes, int n_in,
                              void* d_out, int out_size, void* d_ws, size_t ws_size,
                              hipStream_t stream){
  const float* token = (const float*)d_in[0];
  const float* Wk    = (const float*)d_in[1];
  const float* bk    = (const float*)d_in[2];
  const float* Wq    = (const float*)d_in[3];
  const float* bq    = (const float*)d_in[4];
  const float* Wv    = (const float*)d_in[5];
  const float* bv    = (const float*)d_in[6];
  const float* g1    = (const float*)d_in[7];
  const float* b1    = (const float*)d_in[8];
  const float* g2    = (const float*)d_in[9];
  const float* b2    = (const float*)d_in[10];

  // Workspace (68 MiB):
  //   [0,2MiB)  WvT bf16 [N][K]
  //   [2MiB,..) key / query / dnode / kstat
  //   X @ 4MiB  (32MiB): tokbf -> P' bf16 [B*G][T] -> y bf16
  //   V @ 36MiB (32MiB): valT bf16 [b][e][t] -> z1 bf16
  // F (16MiB f32) lives in d_out[0..4M floats); fully overwritten by k_ln2.
  char* ws = (char*)d_ws;
  u16*   wvT   = (u16*)ws;
  float* key   = (float*)(ws + (2u<<20));
  float* query = (float*)(ws + (2u<<20) + (64u<<10));
  float* dnode = (float*)(ws + (2u<<20) + (128u<<10));
  float* kstat = (float*)(ws + (2u<<20) + (256u<<10));
  u16* X = (u16*)(ws + (4u<<20));
  u16* V = (u16*)(ws + (36u<<20));
  float* F   = (float*)d_out;
  float* out = (float*)d_out;

  k_prep <<<dim3(BT_/4), 256, 0, stream>>>(token, Wk, bk, Wq, bq, key, query, X);
  k_stats<<<dim3(B_),    256, 0, stream>>>(key, query, kstat);
  k_wvT  <<<dim3(E_/32, E_/32), 256, 0, stream>>>(Wv, wvT);
  // value GEMM: A=tokbf (X) -> valT (V), +bias
  k_gemm<0><<<dim3((BT_/128)*(E_/128)), 256, 0, stream>>>(X, wvT, bv, nullptr, V);
  // grid-node P' (tokbf dead -> X reused) + exact per-node denominators
  k_pgen <<<dim3(B_*G_/4), 256, 0, stream>>>(key, kstat, X, dnode);
  // F = normalized grid softmax-averages (into d_out scratch)
  k_fgemm<<<dim3((B_*G_/128)*(E_/64)), 256, 0, stream>>>(X, V, dnode, F);
  // fused interp + LN1: z1 (V; valT dead)
  k_lni  <<<dim3(BT_/4), 256, 0, stream>>>(query, kstat, F, g1, b1, V);
  // gemm2 + residual: A=resid=z1 (V) -> y (X; P' dead)
  k_gemm<1><<<dim3((BT_/128)*(E_/128)), 256, 0, stream>>>(V, wvT, bv, V, X);
  // LN2 + relu -> out (overwrites F region fully)
  k_ln2  <<<dim3(BT_/4), 256, 0, stream>>>(X, g2, b2, out);
}

// Round 10
// 253.861 us; speedup vs baseline: 2.6817x; 1.0200x over previous
//
#include <hip/hip_runtime.h>
#include <cstdint>
#include <cstddef>

// Problem shape (fixed by setup_inputs): B=4, T=4096, E=1024
#define B_ 4
#define T_ 4096
#define E_ 1024
#define BT_ (B_*T_)
#define G_ 1024          // q-grid nodes per batch

typedef unsigned short u16;
typedef unsigned int   u32;
typedef __attribute__((ext_vector_type(8))) short bf8;   // 8 x bf16 (4 VGPRs)
typedef __attribute__((ext_vector_type(4))) float f4;

__device__ inline u16 f2bf(float f){            // RNE float->bf16
  u32 x = __float_as_uint(f);
  u32 r = (x + 0x7fffu + ((x >> 16) & 1u)) >> 16;
  return (u16)r;
}
__device__ inline float bf2f(u32 u){ return __uint_as_float(u << 16); }

__device__ inline float wredsum(float v){
  #pragma unroll
  for (int o = 32; o; o >>= 1) v += __shfl_xor(v, o, 64);
  return v;
}

// raw hardware exp2 (no ocml denormal fixup); safe here: arg <= 0, underflow->0
__device__ inline float hw_exp2(float x){
#if __has_builtin(__builtin_amdgcn_exp2f)
  return __builtin_amdgcn_exp2f(x);
#else
  return exp2f(x);
#endif
}

// async global->LDS, 16B per lane; LDS dest is wave-uniform base + lane*16
__device__ inline void gld_lds16(const void* g, void* l){
  __builtin_amdgcn_global_load_lds(
      (const __attribute__((address_space(1))) void*)g,
      (__attribute__((address_space(3))) void*)l, 16, 0, 0);
}

#define LOG2E_ 1.44269504088896340f

// ---- K1: key/query scalars + bf16 token copy (one wave per row) ------------
__global__ __launch_bounds__(256) void k_prep(const float* __restrict__ token,
    const float* __restrict__ Wk, const float* __restrict__ bk,
    const float* __restrict__ Wq, const float* __restrict__ bq,
    float* __restrict__ key, float* __restrict__ query, u16* __restrict__ tokbf){
  int row  = blockIdx.x * 4 + (threadIdx.x >> 6);
  int lane = threadIdx.x & 63;
  const f4* tr = (const f4*)(token + (size_t)row * E_);
  const f4* wk = (const f4*)Wk;
  const f4* wq = (const f4*)Wq;
  float sk = 0.f, sq = 0.f;
  #pragma unroll
  for (int it = 0; it < 4; ++it){
    f4 t = tr[lane + 64*it];
    f4 a = wk[lane + 64*it];
    f4 b = wq[lane + 64*it];
    sk += t.x*a.x + t.y*a.y + t.z*a.z + t.w*a.w;
    sq += t.x*b.x + t.y*b.y + t.z*b.z + t.w*b.w;
    u32 lo = (u32)f2bf(t.x) | ((u32)f2bf(t.y) << 16);
    u32 hi = (u32)f2bf(t.z) | ((u32)f2bf(t.w) << 16);
    uint2 pk; pk.x = lo; pk.y = hi;
    *(uint2*)(tokbf + (size_t)row * E_ + (lane + 64*it)*4) = pk;
  }
  sk = wredsum(sk); sq = wredsum(sq);
  if (lane == 0){ key[row] = sk + bk[0]; query[row] = sq + bq[0]; }
}

// ---- K2: per-batch kmax/kmin/qmax/qmin -------------------------------------
__global__ __launch_bounds__(256) void k_stats(const float* __restrict__ key,
    const float* __restrict__ query, float* __restrict__ kstat){
  int b = blockIdx.x;
  float kmx = -3.4e38f, kmn = 3.4e38f, qmx = -3.4e38f, qmn = 3.4e38f;
  for (int i = threadIdx.x; i < T_; i += 256){
    float kv = key[b*T_ + i], qv = query[b*T_ + i];
    kmx = fmaxf(kmx, kv); kmn = fminf(kmn, kv);
    qmx = fmaxf(qmx, qv); qmn = fminf(qmn, qv);
  }
  #pragma unroll
  for (int o = 32; o; o >>= 1){
    kmx = fmaxf(kmx, __shfl_xor(kmx, o, 64));
    kmn = fminf(kmn, __shfl_xor(kmn, o, 64));
    qmx = fmaxf(qmx, __shfl_xor(qmx, o, 64));
    qmn = fminf(qmn, __shfl_xor(qmn, o, 64));
  }
  __shared__ float sh[4][4];
  int w = threadIdx.x >> 6;
  if ((threadIdx.x & 63) == 0){
    sh[w][0] = kmx; sh[w][1] = kmn; sh[w][2] = qmx; sh[w][3] = qmn;
  }
  __syncthreads();
  if (threadIdx.x == 0){
    kmx = fmaxf(fmaxf(sh[0][0], sh[1][0]), fmaxf(sh[2][0], sh[3][0]));
    kmn = fminf(fminf(sh[0][1], sh[1][1]), fminf(sh[2][1], sh[3][1]));
    qmx = fmaxf(fmaxf(sh[0][2], sh[1][2]), fmaxf(sh[2][2], sh[3][2]));
    qmn = fminf(fminf(sh[0][3], sh[1][3]), fminf(sh[2][3], sh[3][3]));
    kstat[b*4+0] = kmx; kstat[b*4+1] = kmn;
    kstat[b*4+2] = qmx; kstat[b*4+3] = qmn;
  }
}

// ---- K4: Wv (fp32 [k][n]) -> WvT (bf16 [n][k]) -----------------------------
__global__ __launch_bounds__(256) void k_wvT(const float* __restrict__ Wv,
                                             u16* __restrict__ wvT){
  __shared__ u16 tile[32][33];
  int nt = blockIdx.x, kt = blockIdx.y;
  int tx = threadIdx.x & 31, ty0 = threadIdx.x >> 5;
  #pragma unroll
  for (int p = 0; p < 4; ++p){
    int ty = ty0 + p*8;
    tile[ty][tx] = f2bf(Wv[(size_t)(kt*32+ty)*E_ + nt*32 + tx]);
  }
  __syncthreads();
  #pragma unroll
  for (int p = 0; p < 4; ++p){
    int ty = ty0 + p*8;
    wvT[(size_t)(nt*32+ty)*E_ + kt*32 + tx] = tile[tx][ty];
  }
}

// ---- GEMM: 128x128 tile, 4 waves (2x2, wave tile 64x64), BK=32 -------------
// (unchanged, validated in rounds 2-9)
template<int MODE>
__global__ __launch_bounds__(256) void k_gemm(const u16* __restrict__ A,
    const u16* __restrict__ Bt, const float* __restrict__ bias,
    const u16* __restrict__ resid, u16* __restrict__ outp){
  __shared__ __align__(16) u16 lA[128*32];
  __shared__ __align__(16) u16 lB[128*32];
  const int K = E_, N = E_;
  int bid = blockIdx.x;
  int xcd = bid & 7, rr = bid >> 3;
  int m0 = (xcd + (rr >> 3)*8) * 128;
  int n0 = (rr & 7) * 128;
  int tid = threadIdx.x, lane = tid & 63, w = tid >> 6;
  int wr = w >> 1, wc = w & 1, h = lane >> 4, l15 = lane & 15;
  f4 acc[4][4] = {};
  for (int k0 = 0; k0 < K; k0 += 32){
    __syncthreads();
    #pragma unroll
    for (int p = 0; p < 2; ++p){
      int u = p*256 + w*64 + lane;
      int row = u >> 2;
      int sl  = (u & 3) ^ ((row >> 1) & 3);
      const u16* ga = A  + (size_t)(m0 + row) * K + k0 + sl*8;
      const u16* gb = Bt + (size_t)(n0 + row) * K + k0 + sl*8;
      gld_lds16(ga, lA + (size_t)(p*256 + w*64)*8);
      gld_lds16(gb, lB + (size_t)(p*256 + w*64)*8);
    }
    __syncthreads();
    bf8 a[4], bfr[4];
    #pragma unroll
    for (int f = 0; f < 4; ++f){
      int ra = wr*64 + f*16 + l15;
      int rb = wc*64 + f*16 + l15;
      a[f]   = *(const bf8*)&lA[ra*32 + ((h ^ ((ra >> 1) & 3)) & 3)*8];
      bfr[f] = *(const bf8*)&lB[rb*32 + ((h ^ ((rb >> 1) & 3)) & 3)*8];
    }
    #pragma unroll
    for (int fm = 0; fm < 4; ++fm)
    #pragma unroll
    for (int fn = 0; fn < 4; ++fn)
      acc[fm][fn] = __builtin_amdgcn_mfma_f32_16x16x32_bf16(a[fm], bfr[fn], acc[fm][fn], 0,0,0);
  }
  if (MODE == 0){
    #pragma unroll
    for (int fm = 0; fm < 4; ++fm){
      int rowg = m0 + wr*64 + fm*16 + h*4;
      int bb = rowg >> 12;
      int tt = rowg & (T_-1);
      #pragma unroll
      for (int fn = 0; fn < 4; ++fn){
        int col = n0 + wc*64 + fn*16 + l15;
        float bv = bias[col];
        u16 q0 = f2bf(acc[fm][fn][0] + bv);
        u16 q1 = f2bf(acc[fm][fn][1] + bv);
        u16 q2 = f2bf(acc[fm][fn][2] + bv);
        u16 q3 = f2bf(acc[fm][fn][3] + bv);
        uint2 pk; pk.x = (u32)q0 | ((u32)q1 << 16); pk.y = (u32)q2 | ((u32)q3 << 16);
        *(uint2*)(outp + ((size_t)bb*E_ + col)*T_ + tt) = pk;
      }
    }
  } else {
    #pragma unroll
    for (int fm = 0; fm < 4; ++fm)
    #pragma unroll
    for (int fn = 0; fn < 4; ++fn)
    #pragma unroll
    for (int r = 0; r < 4; ++r){
      int row = m0 + wr*64 + fm*16 + h*4 + r;
      int col = n0 + wc*64 + fn*16 + l15;
      float v = acc[fm][fn][r] + bias[col] + bf2f(resid[(size_t)row * N + col]);
      outp[(size_t)row * N + col] = f2bf(v);
    }
  }
}

// ---- K5: P'-gen — P'[b*G+i][x] = bf16(exp2(g_i k_x - m_i)), d_i = row sum ---
__global__ __launch_bounds__(256) void k_pgen(const float* __restrict__ key,
    const float* __restrict__ kstat, u16* __restrict__ P,
    float* __restrict__ dnode){
  int r    = blockIdx.x * 4 + (threadIdx.x >> 6);   // 0..B*G-1
  int lane = threadIdx.x & 63;
  int b = r >> 10, i = r & (G_-1);
  float kmax = kstat[b*4+0], kmin = kstat[b*4+1];
  float qmax = kstat[b*4+2], qmin = kstat[b*4+3];
  float g = qmin + (qmax - qmin) * ((float)i * (1.f/(G_-1)));
  float m = (g > 0.f) ? g*kmax : g*kmin;
  float gL = g * LOG2E_, mL = m * LOG2E_;
  const f4* kb = (const f4*)(key + (size_t)b * T_);
  u16* pr = P + (size_t)r * T_;
  float s = 0.f;
  #pragma unroll 4
  for (int it = 0; it < 16; ++it){
    f4 kv = kb[lane + it*64];
    u16 e0 = f2bf(hw_exp2(gL*kv.x - mL));
    u16 e1 = f2bf(hw_exp2(gL*kv.y - mL));
    u16 e2 = f2bf(hw_exp2(gL*kv.z - mL));
    u16 e3 = f2bf(hw_exp2(gL*kv.w - mL));
    s += bf2f(e0) + bf2f(e1) + bf2f(e2) + bf2f(e3);   // d matches what GEMM sums
    uint2 pk;
    pk.x = (u32)e0 | ((u32)e1 << 16);
    pk.y = (u32)e2 | ((u32)e3 << 16);
    *(uint2*)(pr + (size_t)(lane + it*64)*4) = pk;
  }
  s = wredsum(s);
  if (lane == 0) dnode[r] = s;
}

// ---- K6 v2: F-GEMM split-K=2 — F[ks][b*G+i][e] = (P'@valT^T)_half(ks)/d_i --
// 1024 blocks (4/CU). XCD-aware: each XCD owns a contiguous 4-m-tile stripe
// (A panel L2-resident, reused by all 16 n-tiles x 2 K-halves). Inner loop is
// the validated round-9 structure, K range halved.
__global__ __launch_bounds__(256) void k_fgemm(const u16* __restrict__ A,
    const u16* __restrict__ Vt, const float* __restrict__ dnode,
    float* __restrict__ F){
  __shared__ __align__(16) u16 lA[128*32];
  __shared__ __align__(16) u16 lB[64*32];
  const int K = T_;
  int bid = blockIdx.x;                 // 1024 blocks
  int xcd = bid & 7;
  int r   = bid >> 3;                   // 0..127
  int ks  = r & 1;                      // K-half
  int n0  = ((r >> 1) & 15) * 64;
  int m0  = (xcd * 4 + (r >> 5)) * 128; // 32 m-tiles, 4 per XCD
  int b   = m0 >> 10;                   // G_=1024 rows per batch
  const u16* Bt = Vt + (size_t)b * E_ * T_;
  int k_beg = ks * (T_/2), k_end = k_beg + (T_/2);
  int tid = threadIdx.x, lane = tid & 63, w = tid >> 6;
  int wr = w >> 1, wc = w & 1, h = lane >> 4, l15 = lane & 15;
  f4 acc[4][2] = {};
  for (int k0 = k_beg; k0 < k_end; k0 += 32){
    __syncthreads();
    #pragma unroll
    for (int p = 0; p < 3; ++p){        // 2x A (128 rows) + 1x B (64 rows)
      int u = p*256 + w*64 + lane;
      if (p < 2){
        int row = u >> 2;
        int sl  = (u & 3) ^ ((row >> 1) & 3);
        gld_lds16(A + (size_t)(m0 + row) * K + k0 + sl*8,
                  lA + (size_t)(p*256 + w*64)*8);
      } else {
        int v = u - 512;
        int row = v >> 2;
        int sl  = (v & 3) ^ ((row >> 1) & 3);
        gld_lds16(Bt + (size_t)(n0 + row) * K + k0 + sl*8,
                  lB + (size_t)(w*64)*8);
      }
    }
    __syncthreads();
    bf8 a[4], bb[2];
    #pragma unroll
    for (int f = 0; f < 4; ++f){
      int ra = wr*64 + f*16 + l15;
      a[f] = *(const bf8*)&lA[ra*32 + ((h ^ ((ra >> 1) & 3)) & 3)*8];
    }
    #pragma unroll
    for (int f = 0; f < 2; ++f){
      int rb = wc*32 + f*16 + l15;
      bb[f] = *(const bf8*)&lB[rb*32 + ((h ^ ((rb >> 1) & 3)) & 3)*8];
    }
    #pragma unroll
    for (int fm = 0; fm < 4; ++fm)
    #pragma unroll
    for (int fn = 0; fn < 2; ++fn)
      acc[fm][fn] = __builtin_amdgcn_mfma_f32_16x16x32_bf16(a[fm], bb[fn], acc[fm][fn], 0,0,0);
  }
  float* Fh = F + (size_t)ks * (B_*G_) * E_;
  #pragma unroll
  for (int fm = 0; fm < 4; ++fm)
  #pragma unroll
  for (int rr = 0; rr < 4; ++rr){
    int row = m0 + wr*64 + fm*16 + h*4 + rr;
    float inv = 1.f / dnode[row];
    #pragma unroll
    for (int fn = 0; fn < 2; ++fn){
      int col = n0 + wc*32 + fn*16 + l15;
      Fh[(size_t)row * E_ + col] = acc[fm][fn][rr] * inv;
    }
  }
}

// ---- K7: interp + LN1 fused — z1[t] = LN(lerp(F0+F1, q_t)) ------------------
__global__ __launch_bounds__(256) void k_lni(const float* __restrict__ query,
    const float* __restrict__ kstat, const float* __restrict__ F,
    const float* __restrict__ g, const float* __restrict__ bt,
    u16* __restrict__ z1){
  int row  = blockIdx.x * 4 + (threadIdx.x >> 6);   // 0..BT-1
  int lane = threadIdx.x & 63;
  int b = row >> 12;                                // T_=4096
  float qmax = kstat[b*4+2], qmin = kstat[b*4+3];
  float q = query[row];
  float u = (q - qmin) * ((float)(G_-1) / (qmax - qmin));
  int i = (int)u;
  if (i < 0) i = 0;
  if (i > G_-2) i = G_-2;
  float a = fminf(fmaxf(u - (float)i, 0.f), 1.f);
  const f4* F0 = (const f4*)(F + ((size_t)(b*G_ + i)) * E_) + lane*4;
  const f4* F1 = F0 + (E_/4);
  const f4* H0 = F0 + (size_t)(B_*G_) * (E_/4);    // second K-half
  const f4* H1 = H0 + (E_/4);
  float v[16];
  #pragma unroll
  for (int jj = 0; jj < 4; ++jj){
    f4 x0 = F0[jj], x1 = F1[jj], y0 = H0[jj], y1 = H1[jj];
    float s0x = x0.x + y0.x, s1x = x1.x + y1.x;
    float s0y = x0.y + y0.y, s1y = x1.y + y1.y;
    float s0z = x0.z + y0.z, s1z = x1.z + y1.z;
    float s0w = x0.w + y0.w, s1w = x1.w + y1.w;
    v[4*jj+0] = s0x + a*(s1x - s0x);
    v[4*jj+1] = s0y + a*(s1y - s0y);
    v[4*jj+2] = s0z + a*(s1z - s0z);
    v[4*jj+3] = s0w + a*(s1w - s0w);
  }
  float s1 = 0.f, s2 = 0.f;
  #pragma unroll
  for (int j = 0; j < 16; ++j){ s1 += v[j]; s2 += v[j]*v[j]; }
  s1 = wredsum(s1); s2 = wredsum(s2);
  float mean = s1 * (1.f/E_);
  float var  = s2 * (1.f/E_) - mean*mean;
  float rs   = rsqrtf(var + 1e-3f);
  const f4* g4 = (const f4*)g + lane*4;
  const f4* b4 = (const f4*)bt + lane*4;
  u16* ob = z1 + (size_t)row * E_ + lane*16;
  u32 pu[8];
  #pragma unroll
  for (int jj = 0; jj < 4; ++jj){
    f4 gg = g4[jj], bb = b4[jj];
    float o0 = (v[4*jj+0]-mean)*rs*gg.x + bb.x;
    float o1 = (v[4*jj+1]-mean)*rs*gg.y + bb.y;
    float o2 = (v[4*jj+2]-mean)*rs*gg.z + bb.z;
    float o3 = (v[4*jj+3]-mean)*rs*gg.w + bb.w;
    pu[2*jj]   = (u32)f2bf(o0) | ((u32)f2bf(o1) << 16);
    pu[2*jj+1] = (u32)f2bf(o2) | ((u32)f2bf(o3) << 16);
  }
  uint4 w0 = {pu[0], pu[1], pu[2], pu[3]};
  uint4 w1 = {pu[4], pu[5], pu[6], pu[7]};
  *(uint4*)ob       = w0;
  *(uint4*)(ob + 8) = w1;
}

// ---- LN2 + relu -> fp32 out -------------------------------------------------
__global__ __launch_bounds__(256) void k_ln2(const u16* __restrict__ in,
    const float* __restrict__ g, const float* __restrict__ bt,
    float* __restrict__ outp){
  int row  = blockIdx.x * 4 + (threadIdx.x >> 6);
  int lane = threadIdx.x & 63;
  const u16* r = in + (size_t)row * E_;
  uint4 u0 = *(const uint4*)(r + lane*16);
  uint4 u1 = *(const uint4*)(r + lane*16 + 8);
  u32 uu[8] = {u0.x, u0.y, u0.z, u0.w, u1.x, u1.y, u1.z, u1.w};
  float v[16];
  #pragma unroll
  for (int j = 0; j < 8; ++j){
    v[2*j]   = bf2f(uu[j] & 0xffffu);
    v[2*j+1] = bf2f(uu[j] >> 16);
  }
  float s1 = 0.f, s2 = 0.f;
  #pragma unroll
  for (int j = 0; j < 16; ++j){ s1 += v[j]; s2 += v[j]*v[j]; }
  s1 = wredsum(s1); s2 = wredsum(s2);
  float mean = s1 * (1.f/E_);
  float var  = s2 * (1.f/E_) - mean*mean;
  float rs   = rsqrtf(var + 1e-3f);
  const f4* g4 = (const f4*)g + lane*4;
  const f4* b4 = (const f4*)bt + lane*4;
  f4* od = (f4*)(outp + (size_t)row * E_ + lane*16);
  #pragma unroll
  for (int jj = 0; jj < 4; ++jj){
    f4 gg = g4[jj], bb = b4[jj];
    f4 t;
    t.x = fmaxf((v[4*jj+0]-mean)*rs*gg.x + bb.x, 0.f);
    t.y = fmaxf((v[4*jj+1]-mean)*rs*gg.y + bb.y, 0.f);
    t.z = fmaxf((v[4*jj+2]-mean)*rs*gg.z + bb.z, 0.f);
    t.w = fmaxf((v[4*jj+3]-mean)*rs*gg.w + bb.w, 0.f);
    od[jj] = t;
  }
}

// ---------------------------------------------------------------------------
extern "C" void kernel_launch(void* const* d_in, const int* in_sizes, int n_in,
                              void* d_out, int out_size, void* d_ws, size_t ws_size,
                              hipStream_t stream){
  const float* token = (const float*)d_in[0];
  const float* Wk    = (const float*)d_in[1];
  const float* bk    = (const float*)d_in[2];
  const float* Wq    = (const float*)d_in[3];
  const float* bq    = (const float*)d_in[4];
  const float* Wv    = (const float*)d_in[5];
  const float* bv    = (const float*)d_in[6];
  const float* g1    = (const float*)d_in[7];
  const float* b1    = (const float*)d_in[8];
  const float* g2    = (const float*)d_in[9];
  const float* b2    = (const float*)d_in[10];

  // Workspace (68 MiB):
  //   [0,2MiB)  WvT bf16 [N][K]
  //   [2MiB,..) key / query / dnode / kstat
  //   X @ 4MiB  (32MiB): tokbf -> P' bf16 [B*G][T] -> y bf16
  //   V @ 36MiB (32MiB): valT bf16 [b][e][t] -> z1 bf16
  // F halves (2 x 16MiB fp32) live in d_out; fully overwritten by k_ln2.
  char* ws = (char*)d_ws;
  u16*   wvT   = (u16*)ws;
  float* key   = (float*)(ws + (2u<<20));
  float* query = (float*)(ws + (2u<<20) + (64u<<10));
  float* dnode = (float*)(ws + (2u<<20) + (128u<<10));
  float* kstat = (float*)(ws + (2u<<20) + (256u<<10));
  u16* X = (u16*)(ws + (4u<<20));
  u16* V = (u16*)(ws + (36u<<20));
  float* F   = (float*)d_out;
  float* out = (float*)d_out;

  k_prep <<<dim3(BT_/4), 256, 0, stream>>>(token, Wk, bk, Wq, bq, key, query, X);
  k_stats<<<dim3(B_),    256, 0, stream>>>(key, query, kstat);
  k_wvT  <<<dim3(E_/32, E_/32), 256, 0, stream>>>(Wv, wvT);
  // value GEMM: A=tokbf (X) -> valT (V), +bias
  k_gemm<0><<<dim3((BT_/128)*(E_/128)), 256, 0, stream>>>(X, wvT, bv, nullptr, V);
  // grid-node P' (tokbf dead -> X reused) + exact per-node denominators
  k_pgen <<<dim3(B_*G_/4), 256, 0, stream>>>(key, kstat, X, dnode);
  // F halves = normalized grid softmax-averages (split-K=2, into d_out)
  k_fgemm<<<dim3((B_*G_/128)*(E_/64)*2), 256, 0, stream>>>(X, V, dnode, F);
  // fused interp(F0+F1) + LN1: z1 (V; valT dead)
  k_lni  <<<dim3(BT_/4), 256, 0, stream>>>(query, kstat, F, g1, b1, V);
  // gemm2 + residual: A=resid=z1 (V) -> y (X; P' dead)
  k_gemm<1><<<dim3((BT_/128)*(E_/128)), 256, 0, stream>>>(V, wvT, bv, V, X);
  // LN2 + relu -> out (overwrites F region fully)
  k_ln2  <<<dim3(BT_/4), 256, 0, stream>>>(X, g2, b2, out);
}

// Round 11
// 206.640 us; speedup vs baseline: 3.2945x; 1.2285x over previous
//
#include <hip/hip_runtime.h>
#include <cstdint>
#include <cstddef>

// Problem shape (fixed by setup_inputs): B=4, T=4096, E=1024
#define B_ 4
#define T_ 4096
#define E_ 1024
#define BT_ (B_*T_)
#define G_ 1024          // q-grid nodes per batch

typedef unsigned short u16;
typedef unsigned int   u32;
typedef __attribute__((ext_vector_type(8))) short bf8;   // 8 x bf16 (4 VGPRs)
typedef __attribute__((ext_vector_type(4))) float f4;

__device__ inline u16 f2bf(float f){            // RNE float->bf16
  u32 x = __float_as_uint(f);
  u32 r = (x + 0x7fffu + ((x >> 16) & 1u)) >> 16;
  return (u16)r;
}
__device__ inline float bf2f(u32 u){ return __uint_as_float(u << 16); }

__device__ inline float wredsum(float v){
  #pragma unroll
  for (int o = 32; o; o >>= 1) v += __shfl_xor(v, o, 64);
  return v;
}

// raw hardware exp2 (no ocml denormal fixup); safe here: arg <= 0, underflow->0
__device__ inline float hw_exp2(float x){
#if __has_builtin(__builtin_amdgcn_exp2f)
  return __builtin_amdgcn_exp2f(x);
#else
  return exp2f(x);
#endif
}

// async global->LDS, 16B per lane; LDS dest is wave-uniform base + lane*16
__device__ inline void gld_lds16(const void* g, void* l){
  __builtin_amdgcn_global_load_lds(
      (const __attribute__((address_space(1))) void*)g,
      (__attribute__((address_space(3))) void*)l, 16, 0, 0);
}

#define LOG2E_ 1.44269504088896340f

// ---- K1: key/query scalars + bf16 token copy (one wave per row) ------------
__global__ __launch_bounds__(256) void k_prep(const float* __restrict__ token,
    const float* __restrict__ Wk, const float* __restrict__ bk,
    const float* __restrict__ Wq, const float* __restrict__ bq,
    float* __restrict__ key, float* __restrict__ query, u16* __restrict__ tokbf){
  int row  = blockIdx.x * 4 + (threadIdx.x >> 6);
  int lane = threadIdx.x & 63;
  const f4* tr = (const f4*)(token + (size_t)row * E_);
  const f4* wk = (const f4*)Wk;
  const f4* wq = (const f4*)Wq;
  float sk = 0.f, sq = 0.f;
  #pragma unroll
  for (int it = 0; it < 4; ++it){
    f4 t = tr[lane + 64*it];
    f4 a = wk[lane + 64*it];
    f4 b = wq[lane + 64*it];
    sk += t.x*a.x + t.y*a.y + t.z*a.z + t.w*a.w;
    sq += t.x*b.x + t.y*b.y + t.z*b.z + t.w*b.w;
    u32 lo = (u32)f2bf(t.x) | ((u32)f2bf(t.y) << 16);
    u32 hi = (u32)f2bf(t.z) | ((u32)f2bf(t.w) << 16);
    uint2 pk; pk.x = lo; pk.y = hi;
    *(uint2*)(tokbf + (size_t)row * E_ + (lane + 64*it)*4) = pk;
  }
  sk = wredsum(sk); sq = wredsum(sq);
  if (lane == 0){ key[row] = sk + bk[0]; query[row] = sq + bq[0]; }
}

// ---- K2: per-batch kmax/kmin/qmax/qmin -------------------------------------
__global__ __launch_bounds__(256) void k_stats(const float* __restrict__ key,
    const float* __restrict__ query, float* __restrict__ kstat){
  int b = blockIdx.x;
  float kmx = -3.4e38f, kmn = 3.4e38f, qmx = -3.4e38f, qmn = 3.4e38f;
  for (int i = threadIdx.x; i < T_; i += 256){
    float kv = key[b*T_ + i], qv = query[b*T_ + i];
    kmx = fmaxf(kmx, kv); kmn = fminf(kmn, kv);
    qmx = fmaxf(qmx, qv); qmn = fminf(qmn, qv);
  }
  #pragma unroll
  for (int o = 32; o; o >>= 1){
    kmx = fmaxf(kmx, __shfl_xor(kmx, o, 64));
    kmn = fminf(kmn, __shfl_xor(kmn, o, 64));
    qmx = fmaxf(qmx, __shfl_xor(qmx, o, 64));
    qmn = fminf(qmn, __shfl_xor(qmn, o, 64));
  }
  __shared__ float sh[4][4];
  int w = threadIdx.x >> 6;
  if ((threadIdx.x & 63) == 0){
    sh[w][0] = kmx; sh[w][1] = kmn; sh[w][2] = qmx; sh[w][3] = qmn;
  }
  __syncthreads();
  if (threadIdx.x == 0){
    kmx = fmaxf(fmaxf(sh[0][0], sh[1][0]), fmaxf(sh[2][0], sh[3][0]));
    kmn = fminf(fminf(sh[0][1], sh[1][1]), fminf(sh[2][1], sh[3][1]));
    qmx = fmaxf(fmaxf(sh[0][2], sh[1][2]), fmaxf(sh[2][2], sh[3][2]));
    qmn = fminf(fminf(sh[0][3], sh[1][3]), fminf(sh[2][3], sh[3][3]));
    kstat[b*4+0] = kmx; kstat[b*4+1] = kmn;
    kstat[b*4+2] = qmx; kstat[b*4+3] = qmn;
  }
}

// ---- K4: Wv (fp32 [k][n]) -> WvT (bf16 [n][k]) -----------------------------
__global__ __launch_bounds__(256) void k_wvT(const float* __restrict__ Wv,
                                             u16* __restrict__ wvT){
  __shared__ u16 tile[32][33];
  int nt = blockIdx.x, kt = blockIdx.y;
  int tx = threadIdx.x & 31, ty0 = threadIdx.x >> 5;
  #pragma unroll
  for (int p = 0; p < 4; ++p){
    int ty = ty0 + p*8;
    tile[ty][tx] = f2bf(Wv[(size_t)(kt*32+ty)*E_ + nt*32 + tx]);
  }
  __syncthreads();
  #pragma unroll
  for (int p = 0; p < 4; ++p){
    int ty = ty0 + p*8;
    wvT[(size_t)(nt*32+ty)*E_ + kt*32 + tx] = tile[tx][ty];
  }
}

// ---- GEMM: 128x128 tile, 4 waves (2x2, wave tile 64x64), BK=32 -------------
// (unchanged, validated in rounds 2-10). Works for any M multiple of 1024
// (m-tiles multiple of 8) via grid size.
template<int MODE>
__global__ __launch_bounds__(256) void k_gemm(const u16* __restrict__ A,
    const u16* __restrict__ Bt, const float* __restrict__ bias,
    const u16* __restrict__ resid, u16* __restrict__ outp){
  __shared__ __align__(16) u16 lA[128*32];
  __shared__ __align__(16) u16 lB[128*32];
  const int K = E_, N = E_;
  int bid = blockIdx.x;
  int xcd = bid & 7, rr = bid >> 3;
  int m0 = (xcd + (rr >> 3)*8) * 128;
  int n0 = (rr & 7) * 128;
  int tid = threadIdx.x, lane = tid & 63, w = tid >> 6;
  int wr = w >> 1, wc = w & 1, h = lane >> 4, l15 = lane & 15;
  f4 acc[4][4] = {};
  for (int k0 = 0; k0 < K; k0 += 32){
    __syncthreads();
    #pragma unroll
    for (int p = 0; p < 2; ++p){
      int u = p*256 + w*64 + lane;
      int row = u >> 2;
      int sl  = (u & 3) ^ ((row >> 1) & 3);
      const u16* ga = A  + (size_t)(m0 + row) * K + k0 + sl*8;
      const u16* gb = Bt + (size_t)(n0 + row) * K + k0 + sl*8;
      gld_lds16(ga, lA + (size_t)(p*256 + w*64)*8);
      gld_lds16(gb, lB + (size_t)(p*256 + w*64)*8);
    }
    __syncthreads();
    bf8 a[4], bfr[4];
    #pragma unroll
    for (int f = 0; f < 4; ++f){
      int ra = wr*64 + f*16 + l15;
      int rb = wc*64 + f*16 + l15;
      a[f]   = *(const bf8*)&lA[ra*32 + ((h ^ ((ra >> 1) & 3)) & 3)*8];
      bfr[f] = *(const bf8*)&lB[rb*32 + ((h ^ ((rb >> 1) & 3)) & 3)*8];
    }
    #pragma unroll
    for (int fm = 0; fm < 4; ++fm)
    #pragma unroll
    for (int fn = 0; fn < 4; ++fn)
      acc[fm][fn] = __builtin_amdgcn_mfma_f32_16x16x32_bf16(a[fm], bfr[fn], acc[fm][fn], 0,0,0);
  }
  if (MODE == 0){
    #pragma unroll
    for (int fm = 0; fm < 4; ++fm){
      int rowg = m0 + wr*64 + fm*16 + h*4;
      int bb = rowg >> 12;
      int tt = rowg & (T_-1);
      #pragma unroll
      for (int fn = 0; fn < 4; ++fn){
        int col = n0 + wc*64 + fn*16 + l15;
        float bv = bias[col];
        u16 q0 = f2bf(acc[fm][fn][0] + bv);
        u16 q1 = f2bf(acc[fm][fn][1] + bv);
        u16 q2 = f2bf(acc[fm][fn][2] + bv);
        u16 q3 = f2bf(acc[fm][fn][3] + bv);
        uint2 pk; pk.x = (u32)q0 | ((u32)q1 << 16); pk.y = (u32)q2 | ((u32)q3 << 16);
        *(uint2*)(outp + ((size_t)bb*E_ + col)*T_ + tt) = pk;
      }
    }
  } else {
    #pragma unroll
    for (int fm = 0; fm < 4; ++fm)
    #pragma unroll
    for (int fn = 0; fn < 4; ++fn)
    #pragma unroll
    for (int r = 0; r < 4; ++r){
      int row = m0 + wr*64 + fm*16 + h*4 + r;
      int col = n0 + wc*64 + fn*16 + l15;
      float v = acc[fm][fn][r] + bias[col] + bf2f(resid[(size_t)row * N + col]);
      outp[(size_t)row * N + col] = f2bf(v);
    }
  }
}

// ---- K5: P'-gen — P'[b*G+i][x] = bf16(exp2(g_i k_x - m_i)), d_i = row sum ---
__global__ __launch_bounds__(256) void k_pgen(const float* __restrict__ key,
    const float* __restrict__ kstat, u16* __restrict__ P,
    float* __restrict__ dnode){
  int r    = blockIdx.x * 4 + (threadIdx.x >> 6);   // 0..B*G-1
  int lane = threadIdx.x & 63;
  int b = r >> 10, i = r & (G_-1);
  float kmax = kstat[b*4+0], kmin = kstat[b*4+1];
  float qmax = kstat[b*4+2], qmin = kstat[b*4+3];
  float g = qmin + (qmax - qmin) * ((float)i * (1.f/(G_-1)));
  float m = (g > 0.f) ? g*kmax : g*kmin;
  float gL = g * LOG2E_, mL = m * LOG2E_;
  const f4* kb = (const f4*)(key + (size_t)b * T_);
  u16* pr = P + (size_t)r * T_;
  float s = 0.f;
  #pragma unroll 4
  for (int it = 0; it < 16; ++it){
    f4 kv = kb[lane + it*64];
    u16 e0 = f2bf(hw_exp2(gL*kv.x - mL));
    u16 e1 = f2bf(hw_exp2(gL*kv.y - mL));
    u16 e2 = f2bf(hw_exp2(gL*kv.z - mL));
    u16 e3 = f2bf(hw_exp2(gL*kv.w - mL));
    s += bf2f(e0) + bf2f(e1) + bf2f(e2) + bf2f(e3);   // d matches what GEMM sums
    uint2 pk;
    pk.x = (u32)e0 | ((u32)e1 << 16);
    pk.y = (u32)e2 | ((u32)e3 << 16);
    *(uint2*)(pr + (size_t)(lane + it*64)*4) = pk;
  }
  s = wredsum(s);
  if (lane == 0) dnode[r] = s;
}

// ---- K6: F-GEMM split-K=2 — F[ks][b*G+i][e] = (P'@valT^T)_half(ks)/d_i -----
// (unchanged, validated round 10)
__global__ __launch_bounds__(256) void k_fgemm(const u16* __restrict__ A,
    const u16* __restrict__ Vt, const float* __restrict__ dnode,
    float* __restrict__ F){
  __shared__ __align__(16) u16 lA[128*32];
  __shared__ __align__(16) u16 lB[64*32];
  const int K = T_;
  int bid = blockIdx.x;                 // 1024 blocks
  int xcd = bid & 7;
  int r   = bid >> 3;                   // 0..127
  int ks  = r & 1;                      // K-half
  int n0  = ((r >> 1) & 15) * 64;
  int m0  = (xcd * 4 + (r >> 5)) * 128; // 32 m-tiles, 4 per XCD
  int b   = m0 >> 10;                   // G_=1024 rows per batch
  const u16* Bt = Vt + (size_t)b * E_ * T_;
  int k_beg = ks * (T_/2), k_end = k_beg + (T_/2);
  int tid = threadIdx.x, lane = tid & 63, w = tid >> 6;
  int wr = w >> 1, wc = w & 1, h = lane >> 4, l15 = lane & 15;
  f4 acc[4][2] = {};
  for (int k0 = k_beg; k0 < k_end; k0 += 32){
    __syncthreads();
    #pragma unroll
    for (int p = 0; p < 3; ++p){        // 2x A (128 rows) + 1x B (64 rows)
      int u = p*256 + w*64 + lane;
      if (p < 2){
        int row = u >> 2;
        int sl  = (u & 3) ^ ((row >> 1) & 3);
        gld_lds16(A + (size_t)(m0 + row) * K + k0 + sl*8,
                  lA + (size_t)(p*256 + w*64)*8);
      } else {
        int v = u - 512;
        int row = v >> 2;
        int sl  = (v & 3) ^ ((row >> 1) & 3);
        gld_lds16(Bt + (size_t)(n0 + row) * K + k0 + sl*8,
                  lB + (size_t)(w*64)*8);
      }
    }
    __syncthreads();
    bf8 a[4], bb[2];
    #pragma unroll
    for (int f = 0; f < 4; ++f){
      int ra = wr*64 + f*16 + l15;
      a[f] = *(const bf8*)&lA[ra*32 + ((h ^ ((ra >> 1) & 3)) & 3)*8];
    }
    #pragma unroll
    for (int f = 0; f < 2; ++f){
      int rb = wc*32 + f*16 + l15;
      bb[f] = *(const bf8*)&lB[rb*32 + ((h ^ ((rb >> 1) & 3)) & 3)*8];
    }
    #pragma unroll
    for (int fm = 0; fm < 4; ++fm)
    #pragma unroll
    for (int fn = 0; fn < 2; ++fn)
      acc[fm][fn] = __builtin_amdgcn_mfma_f32_16x16x32_bf16(a[fm], bb[fn], acc[fm][fn], 0,0,0);
  }
  float* Fh = F + (size_t)ks * (B_*G_) * E_;
  #pragma unroll
  for (int fm = 0; fm < 4; ++fm)
  #pragma unroll
  for (int rr = 0; rr < 4; ++rr){
    int row = m0 + wr*64 + fm*16 + h*4 + rr;
    float inv = 1.f / dnode[row];
    #pragma unroll
    for (int fn = 0; fn < 2; ++fn){
      int col = n0 + wc*32 + fn*16 + l15;
      Fh[(size_t)row * E_ + col] = acc[fm][fn][rr] * inv;
    }
  }
}

// ---- K7: node LN1 — z1node[i] = LN1(F0[i] + F1[i]), bf16 out ----------------
__global__ __launch_bounds__(256) void k_lnn(const float* __restrict__ F,
    const float* __restrict__ g, const float* __restrict__ bt,
    u16* __restrict__ z1){
  int row  = blockIdx.x * 4 + (threadIdx.x >> 6);   // 0..B*G-1
  int lane = threadIdx.x & 63;
  const f4* F0 = (const f4*)(F + (size_t)row * E_) + lane*4;
  const f4* H0 = (const f4*)(F + (size_t)(B_*G_) * E_ + (size_t)row * E_) + lane*4;
  float v[16];
  #pragma unroll
  for (int jj = 0; jj < 4; ++jj){
    f4 x = F0[jj], y = H0[jj];
    v[4*jj+0] = x.x + y.x;
    v[4*jj+1] = x.y + y.y;
    v[4*jj+2] = x.z + y.z;
    v[4*jj+3] = x.w + y.w;
  }
  float s1 = 0.f, s2 = 0.f;
  #pragma unroll
  for (int j = 0; j < 16; ++j){ s1 += v[j]; s2 += v[j]*v[j]; }
  s1 = wredsum(s1); s2 = wredsum(s2);
  float mean = s1 * (1.f/E_);
  float var  = s2 * (1.f/E_) - mean*mean;
  float rs   = rsqrtf(var + 1e-3f);
  const f4* g4 = (const f4*)g + lane*4;
  const f4* b4 = (const f4*)bt + lane*4;
  u16* ob = z1 + (size_t)row * E_ + lane*16;
  u32 pu[8];
  #pragma unroll
  for (int jj = 0; jj < 4; ++jj){
    f4 gg = g4[jj], bb = b4[jj];
    float o0 = (v[4*jj+0]-mean)*rs*gg.x + bb.x;
    float o1 = (v[4*jj+1]-mean)*rs*gg.y + bb.y;
    float o2 = (v[4*jj+2]-mean)*rs*gg.z + bb.z;
    float o3 = (v[4*jj+3]-mean)*rs*gg.w + bb.w;
    pu[2*jj]   = (u32)f2bf(o0) | ((u32)f2bf(o1) << 16);
    pu[2*jj+1] = (u32)f2bf(o2) | ((u32)f2bf(o3) << 16);
  }
  uint4 w0 = {pu[0], pu[1], pu[2], pu[3]};
  uint4 w1 = {pu[4], pu[5], pu[6], pu[7]};
  *(uint4*)ob       = w0;
  *(uint4*)(ob + 8) = w1;
}

// ---- K8: node LN2 (NO relu) — Y[i] = LN2(y2node[i]), fp32 out ---------------
__global__ __launch_bounds__(256) void k_ln2n(const u16* __restrict__ in,
    const float* __restrict__ g, const float* __restrict__ bt,
    float* __restrict__ Y){
  int row  = blockIdx.x * 4 + (threadIdx.x >> 6);   // 0..B*G-1
  int lane = threadIdx.x & 63;
  const u16* r = in + (size_t)row * E_;
  uint4 u0 = *(const uint4*)(r + lane*16);
  uint4 u1 = *(const uint4*)(r + lane*16 + 8);
  u32 uu[8] = {u0.x, u0.y, u0.z, u0.w, u1.x, u1.y, u1.z, u1.w};
  float v[16];
  #pragma unroll
  for (int j = 0; j < 8; ++j){
    v[2*j]   = bf2f(uu[j] & 0xffffu);
    v[2*j+1] = bf2f(uu[j] >> 16);
  }
  float s1 = 0.f, s2 = 0.f;
  #pragma unroll
  for (int j = 0; j < 16; ++j){ s1 += v[j]; s2 += v[j]*v[j]; }
  s1 = wredsum(s1); s2 = wredsum(s2);
  float mean = s1 * (1.f/E_);
  float var  = s2 * (1.f/E_) - mean*mean;
  float rs   = rsqrtf(var + 1e-3f);
  const f4* g4 = (const f4*)g + lane*4;
  const f4* b4 = (const f4*)bt + lane*4;
  f4* od = (f4*)(Y + (size_t)row * E_ + lane*16);
  #pragma unroll
  for (int jj = 0; jj < 4; ++jj){
    f4 gg = g4[jj], bb = b4[jj];
    f4 t;
    t.x = (v[4*jj+0]-mean)*rs*gg.x + bb.x;
    t.y = (v[4*jj+1]-mean)*rs*gg.y + bb.y;
    t.z = (v[4*jj+2]-mean)*rs*gg.z + bb.z;
    t.w = (v[4*jj+3]-mean)*rs*gg.w + bb.w;
    od[jj] = t;
  }
}

// ---- K9: per-token interp + relu — out[t] = relu(lerp(Y, q_t)) --------------
__global__ __launch_bounds__(256) void k_interp(const float* __restrict__ query,
    const float* __restrict__ kstat, const float* __restrict__ Y,
    float* __restrict__ outp){
  int row  = blockIdx.x * 4 + (threadIdx.x >> 6);   // 0..BT-1
  int lane = threadIdx.x & 63;
  int b = row >> 12;                                // T_=4096
  float qmax = kstat[b*4+2], qmin = kstat[b*4+3];
  float q = query[row];
  float u = (q - qmin) * ((float)(G_-1) / (qmax - qmin));
  int i = (int)u;
  if (i < 0) i = 0;
  if (i > G_-2) i = G_-2;
  float a = fminf(fmaxf(u - (float)i, 0.f), 1.f);
  const f4* Y0 = (const f4*)(Y + ((size_t)(b*G_ + i)) * E_) + lane*4;
  const f4* Y1 = Y0 + (E_/4);
  f4* od = (f4*)(outp + (size_t)row * E_ + lane*16);
  #pragma unroll
  for (int jj = 0; jj < 4; ++jj){
    f4 x0 = Y0[jj], x1 = Y1[jj];
    f4 t;
    t.x = fmaxf(x0.x + a*(x1.x - x0.x), 0.f);
    t.y = fmaxf(x0.y + a*(x1.y - x0.y), 0.f);
    t.z = fmaxf(x0.z + a*(x1.z - x0.z), 0.f);
    t.w = fmaxf(x0.w + a*(x1.w - x0.w), 0.f);
    od[jj] = t;
  }
}

// ---------------------------------------------------------------------------
extern "C" void kernel_launch(void* const* d_in, const int* in_sizes, int n_in,
                              void* d_out, int out_size, void* d_ws, size_t ws_size,
                              hipStream_t stream){
  const float* token = (const float*)d_in[0];
  const float* Wk    = (const float*)d_in[1];
  const float* bk    = (const float*)d_in[2];
  const float* Wq    = (const float*)d_in[3];
  const float* bq    = (const float*)d_in[4];
  const float* Wv    = (const float*)d_in[5];
  const float* bv    = (const float*)d_in[6];
  const float* g1    = (const float*)d_in[7];
  const float* b1    = (const float*)d_in[8];
  const float* g2    = (const float*)d_in[9];
  const float* b2    = (const float*)d_in[10];

  // Workspace (68 MiB):
  //   [0,2MiB)  WvT bf16 [N][K]
  //   [2MiB,..) key / query / dnode / kstat
  //   X @ 4MiB  (32MiB): tokbf -> P' bf16 -> {y2node bf16 8MB @X, Ynode fp32 16MB @X+8MB}
  //   V @ 36MiB (32MiB): valT bf16 [b][e][t] -> z1node bf16 (8MB)
  // F halves (2 x 16MiB fp32) live in d_out; fully overwritten by k_interp.
  char* ws = (char*)d_ws;
  u16*   wvT   = (u16*)ws;
  float* key   = (float*)(ws + (2u<<20));
  float* query = (float*)(ws + (2u<<20) + (64u<<10));
  float* dnode = (float*)(ws + (2u<<20) + (128u<<10));
  float* kstat = (float*)(ws + (2u<<20) + (256u<<10));
  u16* X = (u16*)(ws + (4u<<20));
  u16* V = (u16*)(ws + (36u<<20));
  u16*   y2node = X;                                   // 8 MB bf16
  float* Ynode  = (float*)(ws + (4u<<20) + (8u<<20));  // 16 MB fp32
  float* F   = (float*)d_out;
  float* out = (float*)d_out;

  k_prep <<<dim3(BT_/4), 256, 0, stream>>>(token, Wk, bk, Wq, bq, key, query, X);
  k_stats<<<dim3(B_),    256, 0, stream>>>(key, query, kstat);
  k_wvT  <<<dim3(E_/32, E_/32), 256, 0, stream>>>(Wv, wvT);
  // value GEMM: A=tokbf (X) -> valT (V), +bias
  k_gemm<0><<<dim3((BT_/128)*(E_/128)), 256, 0, stream>>>(X, wvT, bv, nullptr, V);
  // grid-node P' (tokbf dead -> X reused) + exact per-node denominators
  k_pgen <<<dim3(B_*G_/4), 256, 0, stream>>>(key, kstat, X, dnode);
  // F halves = normalized grid softmax-averages (split-K=2, into d_out)
  k_fgemm<<<dim3((B_*G_/128)*(E_/64)*2), 256, 0, stream>>>(X, V, dnode, F);
  // node LN1: F0+F1 -> z1node (V; valT dead)
  k_lnn  <<<dim3(B_*G_/4), 256, 0, stream>>>(F, g1, b1, V);
  // node gemm2 + residual: A=resid=z1node (V) -> y2node (X; P' dead)
  k_gemm<1><<<dim3((B_*G_/128)*(E_/128)), 256, 0, stream>>>(V, wvT, bv, V, y2node);
  // node LN2 (no relu) -> Ynode fp32 (X+8MB)
  k_ln2n <<<dim3(B_*G_/4), 256, 0, stream>>>(y2node, g2, b2, Ynode);
  // per-token: relu(lerp(Ynode, q_t)) -> out (overwrites F fully)
  k_interp<<<dim3(BT_/4), 256, 0, stream>>>(query, kstat, Ynode, out);
}